// Round 1
// baseline (38.105 us; speedup 1.0000x reference)
//
#include <hip/hip_runtime.h>
#include <math.h>

// FeedForwardQuantum: the circuit reduces analytically.
// z_j = cos(theta_j) * cos(q_in_j);  exps[w] = prod_{j<=w} z_j (w>=1),
// exps[0] = prod_{j=1..7} z_j.  Then out = relu(exps @ W2^T + b2).

constexpr int EMBED = 768;
constexpr int NQ    = 8;
constexpr int BLOCK = 256;          // 4 waves
constexpr int WAVES = BLOCK / 64;
constexpr int TPW   = 4;            // tokens per wave
constexpr int TPB   = WAVES * TPW;  // 16 tokens per block

__global__ __launch_bounds__(BLOCK, 2) void ffq_kernel(
    const float* __restrict__ x,  const float* __restrict__ W1,
    const float* __restrict__ b1, const float* __restrict__ theta,
    const float* __restrict__ W2, const float* __restrict__ b2,
    float* __restrict__ out, int ntok)
{
    __shared__ float w1s[NQ][EMBED];      // 24 KB, read w1s[q][e], e stride 1 across lanes -> free
    __shared__ float w2s[EMBED][NQ + 1];  // 27.6 KB, pad 9 -> stride-9 across lanes hits all banks
    __shared__ float b2s[EMBED];
    __shared__ float costh[NQ];
    __shared__ float b1s[NQ];

    const int tid = threadIdx.x;
    for (int i = tid; i < NQ * EMBED; i += BLOCK) w1s[i / EMBED][i % EMBED] = W1[i];
    for (int i = tid; i < EMBED * NQ; i += BLOCK) w2s[i / NQ][i % NQ] = W2[i];
    for (int i = tid; i < EMBED; i += BLOCK) b2s[i] = b2[i];
    if (tid < NQ) { costh[tid] = __cosf(theta[tid]); b1s[tid] = b1[tid]; }
    __syncthreads();

    const int wave = tid >> 6;
    const int lane = tid & 63;

    for (int it = 0; it < TPW; ++it) {
        const int t = (blockIdx.x * WAVES + wave) * TPW + it;
        if (t >= ntok) break;
        const float* xrow = x + (size_t)t * EMBED;

        float acc[NQ];
        #pragma unroll
        for (int q = 0; q < NQ; ++q) acc[q] = 0.f;

        // GEMM1 partials: lane owns elements e = lane + 64k (coalesced dword loads)
        #pragma unroll
        for (int k = 0; k < EMBED / 64; ++k) {
            const int e = lane + 64 * k;
            const float xv = xrow[e];
            #pragma unroll
            for (int q = 0; q < NQ; ++q)
                acc[q] = fmaf(xv, w1s[q][e], acc[q]);
        }

        // 64-lane butterfly reduce; every lane ends with all 8 full sums
        #pragma unroll
        for (int q = 0; q < NQ; ++q) {
            float v = acc[q];
            #pragma unroll
            for (int off = 32; off; off >>= 1)
                v += __shfl_xor(v, off, 64);
            acc[q] = v;
        }

        // analytic circuit
        float z[NQ];
        #pragma unroll
        for (int q = 0; q < NQ; ++q)
            z[q] = costh[q] * __cosf(acc[q] + b1s[q]);

        float ex[NQ];
        float pref = z[0];
        #pragma unroll
        for (int q = 1; q < NQ; ++q) { pref *= z[q]; ex[q] = pref; }
        float suf = z[1];
        #pragma unroll
        for (int q = 2; q < NQ; ++q) suf *= z[q];
        ex[0] = suf;

        // GEMM2 + bias + relu: lane owns outputs e = lane + 64k (coalesced stores)
        float* orow = out + (size_t)t * EMBED;
        #pragma unroll
        for (int k = 0; k < EMBED / 64; ++k) {
            const int e = lane + 64 * k;
            float s = b2s[e];
            #pragma unroll
            for (int q = 0; q < NQ; ++q)
                s = fmaf(ex[q], w2s[e][q], s);
            orow[e] = fmaxf(s, 0.f);
        }
    }
}

extern "C" void kernel_launch(void* const* d_in, const int* in_sizes, int n_in,
                              void* d_out, int out_size, void* d_ws, size_t ws_size,
                              hipStream_t stream) {
    const float* x     = (const float*)d_in[0];
    const float* W1    = (const float*)d_in[1];
    const float* b1    = (const float*)d_in[2];
    const float* theta = (const float*)d_in[3];
    const float* W2    = (const float*)d_in[4];
    const float* b2    = (const float*)d_in[5];
    float* out = (float*)d_out;

    const int ntok = in_sizes[0] / EMBED;         // 16384
    const int grid = (ntok + TPB - 1) / TPB;      // 1024
    hipLaunchKernelGGL(ffq_kernel, dim3(grid), dim3(BLOCK), 0, stream,
                       x, W1, b1, theta, W2, b2, out, ntok);
}